// Round 6
// baseline (4247.267 us; speedup 1.0000x reference)
//
// EpisodicMemory: fp32 in/out. Persistent-kernel scan.
//   prep_w  : one-shot fp32->bf16 of fc1_w, W_ih, W_hh.
//   g_kernel: per-b block gate GEMM (unchanged, 130us).
//   persist : ONE kernel, 256 blocks (1/CU, LDS 156KB forces co-residency).
//             Block (jt,bt) owns a 64b x 32j tile. Whh slice (110KB) LDS-resident
//             for all 64 steps. Per 8-step chunk: block computes ITS OWN xg slice
//             (C@Wih^T, block-private -> no sync). Per step: h@Whh^T from LDS,
//             16-block group barrier (device atomics + threadfence; groups are
//             independent b-partitions -> no grid sync). h bf16 hi+lo dbuf in global.
#include <hip/hip_runtime.h>
#include <hip/hip_bf16.h>

#define H_ 512
#define SH_ 120
#define B_ 1024
#define S_ 64

typedef __bf16 bf16x8 __attribute__((ext_vector_type(8)));
typedef float floatx4 __attribute__((ext_vector_type(4)));

__device__ __forceinline__ float bf2f(ushort u) {
    union { unsigned int i; float f; } v; v.i = ((unsigned int)u) << 16; return v.f;
}
__device__ __forceinline__ ushort f2bf(float f) {
    union { float f; unsigned int i; } v; v.f = f;
    unsigned int x = v.i;
    unsigned int r = (x + 0x7fffu + ((x >> 16) & 1u)) >> 16;  // RNE
    return (ushort)r;
}

// ---------------------------------------------------------------------------
__global__ __launch_bounds__(256) void prep_w(
    const float* __restrict__ fc1w, ushort* __restrict__ fc1wb,
    const float* __restrict__ Wih,  ushort* __restrict__ Wihb,
    const float* __restrict__ Whh,  ushort* __restrict__ Whhb)
{
    const int stride = gridDim.x * blockDim.x;
    const int tid = blockIdx.x * blockDim.x + threadIdx.x;
    for (int i = tid; i < 61440; i += stride) {
        const float4 v = ((const float4*)fc1w)[i];
        ushort4 o; o.x = f2bf(v.x); o.y = f2bf(v.y); o.z = f2bf(v.z); o.w = f2bf(v.w);
        ((ushort4*)fc1wb)[i] = o;
    }
    for (int i = tid; i < 196608; i += stride) {
        const float4 v = ((const float4*)Wih)[i];
        ushort4 o; o.x = f2bf(v.x); o.y = f2bf(v.y); o.z = f2bf(v.z); o.w = f2bf(v.w);
        ((ushort4*)Wihb)[i] = o;
    }
    for (int i = tid; i < 196608; i += stride) {
        const float4 v = ((const float4*)Whh)[i];
        ushort4 o; o.x = f2bf(v.x); o.y = f2bf(v.y); o.z = f2bf(v.z); o.w = f2bf(v.w);
        ((ushort4*)Whhb)[i] = o;
    }
}

// ---------------------------------------------------------------------------
// G kernel (unchanged from R5)
// ---------------------------------------------------------------------------
__global__ __launch_bounds__(256) void g_kernel(
    const float* __restrict__ C, const float* __restrict__ Q,
    const float* __restrict__ M, const ushort* __restrict__ fc1wb,
    const float* __restrict__ fc1b, const float* __restrict__ fc2w,
    const float* __restrict__ fc2b, float* __restrict__ G)
{
    __shared__ float qrow[H_];
    __shared__ float mrow[H_];
    __shared__ __align__(16) ushort featT[64 * 72];
    __shared__ __align__(16) ushort wT[128 * 72];
    __shared__ float h1s[64 * 132];

    const int b = blockIdx.x;
    const int t = threadIdx.x;
    for (int i = t; i < H_; i += 256) { qrow[i] = Q[(size_t)b * H_ + i]; mrow[i] = M[(size_t)b * H_ + i]; }

    const int wrow = t >> 1;
    const int wc0  = (t & 1) * 32;
    if (wrow >= SH_) {
        uint4* dst = (uint4*)&wT[wrow * 72 + wc0];
        const uint4 z = {0u, 0u, 0u, 0u};
        dst[0] = z; dst[1] = z; dst[2] = z; dst[3] = z;
    }
    __syncthreads();

    const int lane = t & 63;
    const int wv   = t >> 6;
    const int quad = lane >> 4;
    const int l15  = lane & 15;
    const int arow = wv * 16 + l15;
    const int s    = t >> 2;
    const int c0   = (t & 3) * 16;

    floatx4 acc[8];
#pragma unroll
    for (int i = 0; i < 8; ++i) acc[i] = (floatx4){0.f, 0.f, 0.f, 0.f};

    for (int hc = 0; hc < H_; hc += 64) {
        float cr[16];
        {
            const float4* csrc = (const float4*)(C + ((size_t)b * S_ + s) * H_ + hc + c0);
            *(float4*)&cr[0]  = csrc[0];
            *(float4*)&cr[4]  = csrc[1];
            *(float4*)&cr[8]  = csrc[2];
            *(float4*)&cr[12] = csrc[3];
        }
#pragma unroll
        for (int seg = 0; seg < 4; ++seg) {
#pragma unroll
            for (int u = 0; u < 16; ++u) {
                const int kk = c0 + u;
                const float c = cr[u];
                const float o = (seg == 0 || seg == 2) ? qrow[hc + kk] : mrow[hc + kk];
                const float v = (seg < 2) ? c * o : fabsf(c - o);
                featT[s * 72 + kk] = f2bf(v);
            }
            if (wrow < SH_) {
                const uint4* src = (const uint4*)(fc1wb + (size_t)wrow * (4 * H_) + seg * H_ + hc + wc0);
                uint4* dst = (uint4*)&wT[wrow * 72 + wc0];
                dst[0] = src[0]; dst[1] = src[1]; dst[2] = src[2]; dst[3] = src[3];
            }
            __syncthreads();
#pragma unroll
            for (int ks = 0; ks < 64; ks += 32) {
                const int ao = ks + quad * 8;
                const bf16x8 af = *(const bf16x8*)&featT[arow * 72 + ao];
#pragma unroll
                for (int nt = 0; nt < 8; ++nt) {
                    const bf16x8 bfr = *(const bf16x8*)&wT[(nt * 16 + l15) * 72 + ao];
                    acc[nt] = __builtin_amdgcn_mfma_f32_16x16x32_bf16(af, bfr, acc[nt], 0, 0, 0);
                }
            }
            __syncthreads();
        }
    }

#pragma unroll
    for (int nt = 0; nt < 8; ++nt) {
        const int col = nt * 16 + l15;
        const float bias = (col < SH_) ? fc1b[col] : 0.f;
#pragma unroll
        for (int r = 0; r < 4; ++r) {
            const int row = wv * 16 + quad * 4 + r;
            h1s[row * 132 + col] = (col < SH_) ? tanhf(acc[nt][r] + bias) : 0.f;
        }
    }
    __syncthreads();
    {
        const int part = t & 3;
        float sum = 0.f;
        for (int k = part; k < SH_; k += 4) sum += h1s[s * 132 + k] * fc2w[k];
        sum += __shfl_xor(sum, 1);
        sum += __shfl_xor(sum, 2);
        if (part == 0) {
            const float logit = sum + fc2b[0];
            G[(size_t)b * S_ + s] = 1.f / (1.f + expf(-logit));
        }
    }
}

// ---------------------------------------------------------------------------
// persist: LDS layout (ushort elems): WhhL[8*96*72=55296] | Hb[2*2*64*72=18432]
//          | Xs[6144]  -> total 79872 elems = 159744 B dynamic LDS.
// ---------------------------------------------------------------------------
__global__ __launch_bounds__(256) void persist(
    const float* __restrict__ C, const ushort* __restrict__ Wihb,
    const ushort* __restrict__ Whhb, const float* __restrict__ bih,
    const float* __restrict__ bhh, const float* __restrict__ G,
    ushort* __restrict__ xgw,
    ushort* __restrict__ hhi0, ushort* __restrict__ hlo0,
    ushort* __restrict__ hhi1, ushort* __restrict__ hlo1,
    unsigned* __restrict__ ctr, float* __restrict__ out)
{
    extern __shared__ __align__(16) ushort smem[];
    ushort* WhhL = smem;                 // [kci*6912 + row*72 + k8]
    ushort* Hb   = smem + 55296;         // [buf*9216 + tile*4608 + row*72 + k8]
    ushort* Xs   = smem + 55296 + 18432; // xg A-stage [row*72+k] / xgs [row*96+col]

    const int bx  = blockIdx.x;
    const int bt  = (bx & 7) * 2 + (bx >> 7);   // XCD-aware: same bt -> same XCD
    const int jt  = (bx & 127) >> 3;
    const int jb  = jt * 32;
    const int bb  = bt * 64;
    const int t   = threadIdx.x;
    const int lane = t & 63;
    const int wv   = t >> 6;
    const int quad = lane >> 4;
    const int l15  = lane & 15;
    const int arow = wv * 16 + l15;
    ushort* __restrict__ xgp = xgw + (size_t)bx * 49152;

    // ---- load Whh slice resident (once) ----
    for (int kci = 0; kci < 8; ++kci) {
#pragma unroll
        for (int i = 0; i < 3; ++i) {
            const int gidx = i * 256 + t;
            const int row = gidx >> 3, grp = gidx & 7;
            const int gate = row >> 5, jj = row & 31;
            *(uint4*)&WhhL[kci * 6912 + row * 72 + grp * 8] =
                *(const uint4*)(Whhb + (size_t)(gate * H_ + jb + jj) * H_ + kci * 64 + grp * 8);
        }
    }
    __syncthreads();

    for (int c = 0; c < 8; ++c) {
        // ================= xg phase (block-private) =================
        for (int sub = 0; sub < 8; ++sub) {
            floatx4 xacc[6];
#pragma unroll
            for (int i = 0; i < 6; ++i) xacc[i] = (floatx4){0.f, 0.f, 0.f, 0.f};
            for (int kci = 0; kci < 8; ++kci) {
                {   // stage A: 64 m-rows x 64 k, fp32 -> bf16
                    const int arw = t >> 2;
                    const int ac0 = (t & 3) * 16;
                    const int m = sub * 64 + arw;
                    const float4* src = (const float4*)(C +
                        ((size_t)(bb + (m >> 3)) * S_ + c * 8 + (m & 7)) * H_ + kci * 64 + ac0);
                    float cr[16];
                    *(float4*)&cr[0]  = src[0];
                    *(float4*)&cr[4]  = src[1];
                    *(float4*)&cr[8]  = src[2];
                    *(float4*)&cr[12] = src[3];
                    __align__(16) ushort cb[16];
#pragma unroll
                    for (int u = 0; u < 16; ++u) cb[u] = f2bf(cr[u]);
                    uint4* d = (uint4*)&Xs[arw * 72 + ac0];
                    d[0] = ((uint4*)cb)[0]; d[1] = ((uint4*)cb)[1];
                }
#pragma unroll
                for (int i = 0; i < 3; ++i) {  // stage Wih chunk 96x64 into Hb
                    const int gidx = i * 256 + t;
                    const int row = gidx >> 3, grp = gidx & 7;
                    const int gate = row >> 5, jj = row & 31;
                    *(uint4*)&Hb[row * 72 + grp * 8] =
                        *(const uint4*)(Wihb + (size_t)(gate * H_ + jb + jj) * H_ + kci * 64 + grp * 8);
                }
                __syncthreads();
#pragma unroll
                for (int ks = 0; ks < 64; ks += 32) {
                    const int ao = ks + quad * 8;
                    const bf16x8 af = *(const bf16x8*)&Xs[arow * 72 + ao];
#pragma unroll
                    for (int nf = 0; nf < 6; ++nf) {
                        const bf16x8 bw = *(const bf16x8*)&Hb[(nf * 16 + l15) * 72 + ao];
                        xacc[nf] = __builtin_amdgcn_mfma_f32_16x16x32_bf16(af, bw, xacc[nf], 0, 0, 0);
                    }
                }
                __syncthreads();
            }
            // write xg slice (bf16, block-private)
#pragma unroll
            for (int nf = 0; nf < 6; ++nf) {
#pragma unroll
                for (int r = 0; r < 4; ++r) {
                    const int m = sub * 64 + wv * 16 + quad * 4 + r;
                    xgp[m * 96 + nf * 16 + l15] = f2bf(xacc[nf][r]);
                }
            }
        }
        __threadfence();   // own xg stores -> visible to own (cross-thread) loads
        __syncthreads();

        // ================= 8 scan steps =================
        for (int sl = 0; sl < 8; ++sl) {
            const int tstep = c * 8 + sl;
            const ushort* __restrict__ hhi_r = (tstep & 1) ? hhi1 : hhi0;
            const ushort* __restrict__ hlo_r = (tstep & 1) ? hlo1 : hlo0;
            ushort* __restrict__ hhi_w = (tstep & 1) ? hhi0 : hhi1;
            ushort* __restrict__ hlo_w = (tstep & 1) ? hlo0 : hlo1;

            floatx4 acc_r[2], acc_z[2], acc_hn[2];
#pragma unroll
            for (int i = 0; i < 2; ++i) {
                acc_r[i] = (floatx4){0.f,0.f,0.f,0.f};
                acc_z[i] = (floatx4){0.f,0.f,0.f,0.f};
                acc_hn[i]= (floatx4){0.f,0.f,0.f,0.f};
            }

            // stage xgs slice for this sl: 768 uint4
#pragma unroll
            for (int i = 0; i < 3; ++i) {
                const int gid = i * 256 + t;
                const int row = gid / 12;
                const int q   = gid - row * 12;
                *(uint4*)&Xs[row * 96 + q * 8] =
                    *(const uint4*)(xgp + (row * 8 + sl) * 96 + q * 8);
            }
            // stage h chunk 0
#pragma unroll
            for (int i = 0; i < 4; ++i) {
                const int gid  = i * 256 + t;
                const int tile = gid >> 9;
                const int rem  = gid & 511;
                const int row  = rem >> 3, grp = rem & 7;
                *(uint4*)&Hb[tile * 4608 + row * 72 + grp * 8] =
                    *(const uint4*)((tile ? hlo_r : hhi_r) + (size_t)(bb + row) * H_ + grp * 8);
            }
            __syncthreads();

            for (int kci = 0; kci < 8; ++kci) {
                const int cur = kci & 1;
                uint4 hv[4];
                if (kci < 7) {
                    const int kn = (kci + 1) * 64;
#pragma unroll
                    for (int i = 0; i < 4; ++i) {
                        const int gid  = i * 256 + t;
                        const int tile = gid >> 9;
                        const int rem  = gid & 511;
                        const int row  = rem >> 3, grp = rem & 7;
                        hv[i] = *(const uint4*)((tile ? hlo_r : hhi_r) + (size_t)(bb + row) * H_ + kn + grp * 8);
                    }
                }
#pragma unroll
                for (int ks = 0; ks < 64; ks += 32) {
                    const int ao = ks + quad * 8;
                    const bf16x8 a_hh = *(const bf16x8*)&Hb[cur * 9216 + arow * 72 + ao];
                    const bf16x8 a_hl = *(const bf16x8*)&Hb[cur * 9216 + 4608 + arow * 72 + ao];
#pragma unroll
                    for (int nt = 0; nt < 2; ++nt) {
                        const int jj = nt * 16 + l15;
                        const bf16x8 w_r = *(const bf16x8*)&WhhL[kci * 6912 + (0 * 32 + jj) * 72 + ao];
                        const bf16x8 w_z = *(const bf16x8*)&WhhL[kci * 6912 + (1 * 32 + jj) * 72 + ao];
                        const bf16x8 w_n = *(const bf16x8*)&WhhL[kci * 6912 + (2 * 32 + jj) * 72 + ao];
                        acc_r[nt]  = __builtin_amdgcn_mfma_f32_16x16x32_bf16(a_hh, w_r, acc_r[nt],  0, 0, 0);
                        acc_r[nt]  = __builtin_amdgcn_mfma_f32_16x16x32_bf16(a_hl, w_r, acc_r[nt],  0, 0, 0);
                        acc_z[nt]  = __builtin_amdgcn_mfma_f32_16x16x32_bf16(a_hh, w_z, acc_z[nt],  0, 0, 0);
                        acc_z[nt]  = __builtin_amdgcn_mfma_f32_16x16x32_bf16(a_hl, w_z, acc_z[nt],  0, 0, 0);
                        acc_hn[nt] = __builtin_amdgcn_mfma_f32_16x16x32_bf16(a_hh, w_n, acc_hn[nt], 0, 0, 0);
                        acc_hn[nt] = __builtin_amdgcn_mfma_f32_16x16x32_bf16(a_hl, w_n, acc_hn[nt], 0, 0, 0);
                    }
                }
                if (kci < 7) {
                    const int cn = cur ^ 1;
#pragma unroll
                    for (int i = 0; i < 4; ++i) {
                        const int gid  = i * 256 + t;
                        const int tile = gid >> 9;
                        const int rem  = gid & 511;
                        const int row  = rem >> 3, grp = rem & 7;
                        *(uint4*)&Hb[cn * 9216 + tile * 4608 + row * 72 + grp * 8] = hv[i];
                    }
                }
                __syncthreads();
            }

            // epilogue
#pragma unroll
            for (int nt = 0; nt < 2; ++nt) {
                const int jc = nt * 16 + l15;
                const int j  = jb + jc;
                const float br  = bih[j]          + bhh[j];
                const float bz  = bih[H_ + j]     + bhh[H_ + j];
                const float bxn = bih[2 * H_ + j] + 0.f;
                const float bhn = bhh[2 * H_ + j];
#pragma unroll
                for (int r4 = 0; r4 < 4; ++r4) {
                    const int bl = wv * 16 + quad * 4 + r4;
                    const int b  = bb + bl;
                    const size_t idx = (size_t)b * H_ + j;
                    const float xr = bf2f(Xs[bl * 96 + 0 * 32 + jc]);
                    const float xz = bf2f(Xs[bl * 96 + 1 * 32 + jc]);
                    const float xn = bf2f(Xs[bl * 96 + 2 * 32 + jc]);
                    const float hold = bf2f(hhi_r[idx]) + bf2f(hlo_r[idx]);
                    const float g = G[(size_t)b * S_ + tstep];
                    const float rg = 1.f / (1.f + expf(-(acc_r[nt][r4] + xr + br)));
                    const float zg = 1.f / (1.f + expf(-(acc_z[nt][r4] + xz + bz)));
                    const float ng = tanhf(xn + bxn + rg * (acc_hn[nt][r4] + bhn));
                    const float hgru = (1.f - zg) * ng + zg * hold;
                    const float hnew = g * hgru + (1.f - g) * hold;
                    const ushort hb = f2bf(hnew);
                    hhi_w[idx] = hb;
                    hlo_w[idx] = f2bf(hnew - bf2f(hb));
                    if (tstep == S_ - 1) out[idx] = hnew;
                }
            }

            // ---- group barrier (16 blocks sharing bt) ----
            __threadfence();
            __syncthreads();
            if (t == 0) {
                atomicAdd(ctr + bt, 1u);
                const unsigned target = 16u * (unsigned)(tstep + 1);
                while (atomicAdd(ctr + bt, 0u) < target) __builtin_amdgcn_s_sleep(2);
            }
            __syncthreads();
            __threadfence();
        }
    }
}

extern "C" void kernel_launch(void* const* d_in, const int* in_sizes, int n_in,
                              void* d_out, int out_size, void* d_ws, size_t ws_size,
                              hipStream_t stream) {
    (void)in_sizes; (void)n_in; (void)out_size; (void)ws_size;
    const float* C    = (const float*)d_in[0];
    const float* Q    = (const float*)d_in[1];
    const float* M    = (const float*)d_in[2];
    const float* fc1w = (const float*)d_in[3];
    const float* fc1b = (const float*)d_in[4];
    const float* fc2w = (const float*)d_in[5];
    const float* fc2b = (const float*)d_in[6];
    const float* Wih  = (const float*)d_in[7];
    const float* Whh  = (const float*)d_in[8];
    const float* bih  = (const float*)d_in[9];
    const float* bhh  = (const float*)d_in[10];
    float* out = (float*)d_out;

    char* ws = (char*)d_ws;
    float*    Gbuf  = (float*)ws;                          // 256 KB
    ushort*   hhi0  = (ushort*)(ws + 262144);              // 1 MB
    ushort*   hlo0  = (ushort*)(ws + 262144 + 1048576);    // 1 MB
    ushort*   hhi1  = (ushort*)(ws + 262144 + 2097152);    // 1 MB
    ushort*   hlo1  = (ushort*)(ws + 262144 + 3145728);    // 1 MB
    ushort*   fc1wb = (ushort*)(ws + 4456448);             // 480 KB
    ushort*   Wihb  = (ushort*)(ws + 4947968);             // 1.5 MB
    ushort*   Whhb  = (ushort*)(ws + 6520832);             // 1.5 MB
    ushort*   xgw   = (ushort*)(ws + 8093696);             // 24 MB (256*49152*2)
    unsigned* ctr   = (unsigned*)(ws + 8093696 + 25165824);// 64 B

    hipMemsetAsync(hhi0, 0, 2097152, stream);              // h0 = 0 (hi+lo buf0)
    hipMemsetAsync(ctr, 0, 64, stream);                    // barrier counters

    prep_w<<<256, 256, 0, stream>>>(fc1w, fc1wb, Wih, Wihb, Whh, Whhb);
    g_kernel<<<B_, 256, 0, stream>>>(C, Q, M, fc1wb, fc1b, fc2w, fc2b, Gbuf);

    const int lds_bytes = 159744;
    static bool attr_set = false;
    if (!attr_set) {
        hipFuncSetAttribute((const void*)persist,
                            hipFuncAttributeMaxDynamicSharedMemorySize, 160 * 1024);
        attr_set = true;
    }
    persist<<<256, 256, lds_bytes, stream>>>(C, Wihb, Whhb, bih, bhh, Gbuf,
                                             xgw, hhi0, hlo0, hhi1, hlo1, ctr, out);
}